// Round 4
// baseline (493.871 us; speedup 1.0000x reference)
//
#include <hip/hip_runtime.h>
#include <hip/hip_bf16.h>
#include <math.h>

#define BB 2
#define TT 1024
#define SS 1024
#define DD 1024
#define HH 16
#define DH 64

typedef __attribute__((ext_vector_type(8))) short bf16x8;
typedef __attribute__((ext_vector_type(4))) float f32x4;
typedef unsigned short ushort_t;

#define AS3(p) ((__attribute__((address_space(3))) unsigned int*)(p))
#define AS1(p) ((const __attribute__((address_space(1))) unsigned int*)(p))

__device__ __forceinline__ unsigned short f2b(float f) {
    union { float f; unsigned u; } x; x.f = f;
    unsigned r = x.u + 0x7FFFu + ((x.u >> 16) & 1u);
    return (unsigned short)(r >> 16);
}

// ---------------------------------------------------------------------------
// fp32 -> bf16 conversion, all 7 arrays in one launch.
// q/k/v: 2M elems (1024 blocks); Wq/Wk/Wv/Wo: 1M elems (512 blocks).
// ---------------------------------------------------------------------------
__global__ __launch_bounds__(256) void cvt_all(
    const float* __restrict__ q, const float* __restrict__ k, const float* __restrict__ v,
    const float* __restrict__ Wq, const float* __restrict__ Wk,
    const float* __restrict__ Wv, const float* __restrict__ Wo,
    ushort_t* __restrict__ qb, ushort_t* __restrict__ kb, ushort_t* __restrict__ vb,
    ushort_t* __restrict__ Wqb, ushort_t* __restrict__ Wkb,
    ushort_t* __restrict__ Wvb, ushort_t* __restrict__ Wob)
{
    const int z = blockIdx.y;
    if (z >= 3 && blockIdx.x >= 512) return;
    const float* src;
    ushort_t* dst;
    switch (z) {
        case 0: src = q;  dst = qb;  break;
        case 1: src = k;  dst = kb;  break;
        case 2: src = v;  dst = vb;  break;
        case 3: src = Wq; dst = Wqb; break;
        case 4: src = Wk; dst = Wkb; break;
        case 5: src = Wv; dst = Wvb; break;
        default: src = Wo; dst = Wob; break;
    }
    size_t i = ((size_t)blockIdx.x * 256 + threadIdx.x) * 8;
    float4 v0 = *(const float4*)&src[i];
    float4 v1 = *(const float4*)&src[i + 4];
    uint4 o;
    o.x = f2b(v0.x) | ((unsigned)f2b(v0.y) << 16);
    o.y = f2b(v0.z) | ((unsigned)f2b(v0.w) << 16);
    o.z = f2b(v1.x) | ((unsigned)f2b(v1.y) << 16);
    o.w = f2b(v1.z) | ((unsigned)f2b(v1.w) << 16);
    *(uint4*)&dst[i] = o;
}

// ---------------------------------------------------------------------------
// 128x128 bf16 MFMA GEMM mainloop: D = A (MxK) . Bw^T (N x K), both K-contig.
// ---------------------------------------------------------------------------
__device__ __forceinline__ void gemm128_mainloop(
    const ushort_t* __restrict__ A, const ushort_t* __restrict__ Bw,
    int K, ushort_t* Asm, ushort_t* Bsm, f32x4 acc[4][4])
{
    const int tid = threadIdx.x;
    const int wave = tid >> 6, lane = tid & 63;
    const int sr = lane >> 2;
    const int gc = (lane & 3) ^ ((lane >> 3) & 3);
    const int l15 = lane & 15, q = lane >> 4;
    const int mblk = (wave >> 1) * 64, nblk = (wave & 1) * 64;

    for (int k0 = 0; k0 < K; k0 += 32) {
        #pragma unroll
        for (int o = 0; o < 2; o++) {
            int r0 = (wave * 2 + o) * 16;
            __builtin_amdgcn_global_load_lds(AS1(A + (size_t)(r0 + sr) * K + k0 + gc * 8),
                                             AS3(Asm + r0 * 32), 16, 0, 0);
            __builtin_amdgcn_global_load_lds(AS1(Bw + (size_t)(r0 + sr) * K + k0 + gc * 8),
                                             AS3(Bsm + r0 * 32), 16, 0, 0);
        }
        __syncthreads();

        bf16x8 av[4], bv[4];
        #pragma unroll
        for (int mi = 0; mi < 4; mi++) {
            int r = mblk + mi * 16 + l15;
            av[mi] = *(const bf16x8*)&Asm[r * 32 + (q ^ ((r >> 1) & 3)) * 8];
        }
        #pragma unroll
        for (int ni = 0; ni < 4; ni++) {
            int r = nblk + ni * 16 + l15;
            bv[ni] = *(const bf16x8*)&Bsm[r * 32 + (q ^ ((r >> 1) & 3)) * 8];
        }
        #pragma unroll
        for (int mi = 0; mi < 4; mi++)
            #pragma unroll
            for (int ni = 0; ni < 4; ni++)
                acc[mi][ni] = __builtin_amdgcn_mfma_f32_16x16x32_bf16(av[mi], bv[ni], acc[mi][ni], 0, 0, 0);
        __syncthreads();
    }
}

__global__ __launch_bounds__(256) void proj_gemm(
    const ushort_t* __restrict__ qb, const ushort_t* __restrict__ kb, const ushort_t* __restrict__ vb,
    const ushort_t* __restrict__ Wqb, const ushort_t* __restrict__ Wkb, const ushort_t* __restrict__ Wvb,
    const float* __restrict__ bq, const float* __restrict__ bk, const float* __restrict__ bv,
    ushort_t* __restrict__ qh, ushort_t* __restrict__ kh, ushort_t* __restrict__ vh)
{
    __shared__ ushort_t Asm[128 * 32];
    __shared__ ushort_t Bsm[128 * 32];
    const int z = blockIdx.z;
    const ushort_t* A = (z == 0) ? qb : (z == 1) ? kb : vb;
    const ushort_t* W = (z == 0) ? Wqb : (z == 1) ? Wkb : Wvb;
    const float* bias = (z == 0) ? bq : (z == 1) ? bk : bv;
    ushort_t* Y = (z == 0) ? qh : (z == 1) ? kh : vh;

    const int bm = blockIdx.y * 128, bn = blockIdx.x * 128;
    f32x4 acc[4][4];
    #pragma unroll
    for (int i = 0; i < 4; i++)
        #pragma unroll
        for (int j = 0; j < 4; j++) acc[i][j] = (f32x4)(0.f);

    gemm128_mainloop(A + (size_t)bm * DD, W + (size_t)bn * DD, DD, Asm, Bsm, acc);

    const int lane = threadIdx.x & 63, wave = threadIdx.x >> 6;
    const int mblk = (wave >> 1) * 64, nblk = (wave & 1) * 64;
    const int l15 = lane & 15, q = lane >> 4;
    #pragma unroll
    for (int mi = 0; mi < 4; mi++) {
        #pragma unroll
        for (int ni = 0; ni < 4; ni++) {
            int col = bn + nblk + ni * 16 + l15;
            float bcol = bias[col];
            #pragma unroll
            for (int r = 0; r < 4; r++) {
                int row = bm + mblk + mi * 16 + q * 4 + r;
                Y[(size_t)row * DD + col] = f2b(acc[mi][ni][r] + bcol);
            }
        }
    }
}

__global__ __launch_bounds__(256) void oproj_gemm(
    const ushort_t* __restrict__ A, const ushort_t* __restrict__ W,
    const float* __restrict__ bias, float* __restrict__ Y)
{
    __shared__ ushort_t Asm[128 * 32];
    __shared__ ushort_t Bsm[128 * 32];
    const int bm = blockIdx.y * 128, bn = blockIdx.x * 128;
    f32x4 acc[4][4];
    #pragma unroll
    for (int i = 0; i < 4; i++)
        #pragma unroll
        for (int j = 0; j < 4; j++) acc[i][j] = (f32x4)(0.f);

    gemm128_mainloop(A + (size_t)bm * DD, W + (size_t)bn * DD, DD, Asm, Bsm, acc);

    const int lane = threadIdx.x & 63, wave = threadIdx.x >> 6;
    const int mblk = (wave >> 1) * 64, nblk = (wave & 1) * 64;
    const int l15 = lane & 15, q = lane >> 4;
    #pragma unroll
    for (int mi = 0; mi < 4; mi++) {
        #pragma unroll
        for (int ni = 0; ni < 4; ni++) {
            int col = bn + nblk + ni * 16 + l15;
            float bcol = bias[col];
            #pragma unroll
            for (int r = 0; r < 4; r++) {
                int row = bm + mblk + mi * 16 + q * 4 + r;
                Y[(size_t)row * DD + col] = acc[mi][ni][r] + bcol;
            }
        }
    }
}

// ---------------------------------------------------------------------------
// V transpose: vh (B,S,H*DH) bf16 -> vT (B,H,DH,S) bf16
// ---------------------------------------------------------------------------
__global__ __launch_bounds__(256) void transpose_v(
    const ushort_t* __restrict__ vh, ushort_t* __restrict__ vT)
{
    __shared__ ushort_t Ls[64][72];
    const int s0 = blockIdx.x * 64;
    const int bh = blockIdx.y;
    const int b = bh >> 4, h = bh & 15;
    const int tid = threadIdx.x;
    const int r = tid >> 2, c16 = (tid & 3) * 16;

    const ushort_t* src = &vh[((size_t)(b * SS + s0 + r)) * DD + h * DH + c16];
    uint4 u0 = *(const uint4*)src;
    uint4 u1 = *(const uint4*)(src + 8);
    ushort_t tmp[16];
    *(uint4*)&tmp[0] = u0; *(uint4*)&tmp[8] = u1;
    #pragma unroll
    for (int j = 0; j < 16; j++) Ls[c16 + j][r] = tmp[j];
    __syncthreads();

    const int dh = r;
    uint4 w0 = *(const uint4*)&Ls[dh][c16];
    uint4 w1 = *(const uint4*)&Ls[dh][c16 + 8];
    ushort_t* dst = &vT[((size_t)bh * DH + dh) * SS + s0 + c16];
    *(uint4*)dst = w0;
    *(uint4*)(dst + 8) = w1;
}

// ---------------------------------------------------------------------------
// Fused flash attention: per (bh, 64-row t-block).
// P1: MFMA scores -> row maxes (recompute trick, no score storage)
// P2: recompute scores, w = exp(s-m)*scale(bias); w->LDS->wbuf(bf16);
//     l2 += w; O += w.V (MFMA)
// P3: attn = w * inv_l2 (fp32, incl. zero-fill s>t)
// P4: ao = O * inv_l2 (bf16)
// l1 of the first softmax cancels algebraically -> never computed.
// ---------------------------------------------------------------------------
#define SCORE_MFMA(sacc)                                                        \
  do {                                                                          \
    _Pragma("unroll")                                                           \
    for (int ks = 0; ks < 2; ks++) {                                            \
      bf16x8 af[2], bfv[4];                                                     \
      _Pragma("unroll")                                                         \
      for (int mi = 0; mi < 2; mi++) {                                          \
        int row_ = mq * 32 + mi * 16 + l15;                                     \
        af[mi] = *(const bf16x8*)&Qs[row_ * 64 + ((ks * 4 + q) ^ (row_ & 7)) * 8]; \
      }                                                                         \
      _Pragma("unroll")                                                         \
      for (int ni = 0; ni < 4; ni++) {                                          \
        int srw_ = nq * 64 + ni * 16 + l15;                                     \
        bfv[ni] = *(const bf16x8*)&Ks[srw_ * 64 + ((ks * 4 + q) ^ (srw_ & 7)) * 8]; \
      }                                                                         \
      _Pragma("unroll")                                                         \
      for (int mi = 0; mi < 2; mi++)                                            \
        _Pragma("unroll")                                                       \
        for (int ni = 0; ni < 4; ni++)                                          \
          sacc[mi][ni] = __builtin_amdgcn_mfma_f32_16x16x32_bf16(af[mi], bfv[ni], sacc[mi][ni], 0, 0, 0); \
    }                                                                           \
  } while (0)

#define STAGE_K(s0_)                                                            \
  do {                                                                          \
    _Pragma("unroll")                                                           \
    for (int o = 0; o < 4; o++) {                                               \
      int slot = o * 256 + tid;                                                 \
      int row_ = slot >> 3, cs_ = slot & 7, c_ = cs_ ^ (row_ & 7);              \
      __builtin_amdgcn_global_load_lds(                                         \
          AS1(kh + (size_t)(b * SS + (s0_) + row_) * DD + h * DH + c_ * 8),     \
          AS3(Ks + (o * 256 + wave * 64) * 8), 16, 0, 0);                       \
    }                                                                           \
  } while (0)

#define STAGE_V(s0_)                                                            \
  do {                                                                          \
    _Pragma("unroll")                                                           \
    for (int o = 0; o < 4; o++) {                                               \
      int slot = o * 256 + tid;                                                 \
      int row_ = slot >> 4, cs_ = slot & 15, c_ = cs_ ^ (row_ & 15);            \
      __builtin_amdgcn_global_load_lds(                                         \
          AS1(vT + ((size_t)bh * DH + row_) * SS + (s0_) + c_ * 8),             \
          AS3(Vs + (o * 256 + wave * 64) * 8), 16, 0, 0);                       \
    }                                                                           \
  } while (0)

__global__ __launch_bounds__(256, 2) void flash_attn(
    const ushort_t* __restrict__ qh, const ushort_t* __restrict__ kh,
    const ushort_t* __restrict__ vT, const float* __restrict__ attn_bias,
    const float* __restrict__ bscale_p,
    ushort_t* __restrict__ wbuf, ushort_t* __restrict__ ao,
    float* __restrict__ attn)
{
    __shared__ alignas(16) ushort_t Qs[64 * 64];
    __shared__ alignas(16) ushort_t Ks[128 * 64];
    __shared__ alignas(16) ushort_t Vs[64 * 128];
    __shared__ alignas(16) ushort_t Ws[64 * 136];
    __shared__ float rmax_p[2][64];
    __shared__ float rsum_p[2][64];
    __shared__ float rstat[64];

    const int xs = blockIdx.x;
    const int ti = (xs & 1) ? (15 - (xs >> 1)) : (xs >> 1);  // heavy/light pairing
    const int bh = blockIdx.y;
    const int b = bh >> 4, h = bh & 15;
    const int t0 = ti * 64;
    const int nst = (ti >> 1) + 1;     // number of 128-wide s-tiles

    const int tid = threadIdx.x;
    const int wave = tid >> 6, lane = tid & 63;
    const int l15 = lane & 15, q = lane >> 4;
    const int mq = wave & 1, nq = wave >> 1;

    // ---- stage Q once (64 x 64) ----
    #pragma unroll
    for (int o = 0; o < 2; o++) {
        int slot = o * 256 + tid;
        int row_ = slot >> 3, cs_ = slot & 7, c_ = cs_ ^ (row_ & 7);
        __builtin_amdgcn_global_load_lds(
            AS1(qh + (size_t)(b * TT + t0 + row_) * DD + h * DH + c_ * 8),
            AS3(Qs + (o * 256 + wave * 64) * 8), 16, 0, 0);
    }

    // ---- P1: row maxes ----
    float rm[2][4];
    #pragma unroll
    for (int mi = 0; mi < 2; mi++)
        #pragma unroll
        for (int r = 0; r < 4; r++) rm[mi][r] = -INFINITY;

    for (int si = 0; si < nst; si++) {
        const int s0 = si * 128;
        STAGE_K(s0);
        __syncthreads();
        f32x4 sacc[2][4];
        #pragma unroll
        for (int mi = 0; mi < 2; mi++)
            #pragma unroll
            for (int ni = 0; ni < 4; ni++) sacc[mi][ni] = (f32x4)(0.f);
        SCORE_MFMA(sacc);
        #pragma unroll
        for (int mi = 0; mi < 2; mi++)
            #pragma unroll
            for (int ni = 0; ni < 4; ni++) {
                int s = s0 + nq * 64 + ni * 16 + l15;
                #pragma unroll
                for (int r = 0; r < 4; r++) {
                    int t = t0 + mq * 32 + mi * 16 + q * 4 + r;
                    if (s <= t) {
                        float v = fminf(fmaxf(sacc[mi][ni][r] * 0.125f, -80.f), 80.f);
                        rm[mi][r] = fmaxf(rm[mi][r], v);
                    }
                }
            }
        __syncthreads();
    }
    #pragma unroll
    for (int mi = 0; mi < 2; mi++)
        #pragma unroll
        for (int r = 0; r < 4; r++) {
            float v = rm[mi][r];
            v = fmaxf(v, __shfl_xor(v, 1));
            v = fmaxf(v, __shfl_xor(v, 2));
            v = fmaxf(v, __shfl_xor(v, 4));
            v = fmaxf(v, __shfl_xor(v, 8));
            rm[mi][r] = v;
        }
    if (l15 == 0) {
        #pragma unroll
        for (int mi = 0; mi < 2; mi++)
            #pragma unroll
            for (int r = 0; r < 4; r++)
                rmax_p[nq][mq * 32 + mi * 16 + q * 4 + r] = rm[mi][r];
    }
    __syncthreads();
    if (tid < 64) rstat[tid] = fmaxf(rmax_p[0][tid], rmax_p[1][tid]);
    __syncthreads();

    // ---- P2: w, l2, O ----
    float rs[2][4] = {};
    f32x4 oacc[2][2];
    #pragma unroll
    for (int mi = 0; mi < 2; mi++)
        #pragma unroll
        for (int ni = 0; ni < 2; ni++) oacc[mi][ni] = (f32x4)(0.f);
    const float bs = bscale_p[0];

    for (int si = 0; si < nst; si++) {
        const int s0 = si * 128;
        STAGE_K(s0);
        STAGE_V(s0);
        __syncthreads();
        f32x4 sacc[2][4];
        #pragma unroll
        for (int mi = 0; mi < 2; mi++)
            #pragma unroll
            for (int ni = 0; ni < 4; ni++) sacc[mi][ni] = (f32x4)(0.f);
        SCORE_MFMA(sacc);

        #pragma unroll
        for (int mi = 0; mi < 2; mi++)
            #pragma unroll
            for (int ni = 0; ni < 4; ni++) {
                int sc_ = nq * 64 + ni * 16 + l15;
                int s = s0 + sc_;
                #pragma unroll
                for (int r = 0; r < 4; r++) {
                    int trow = mq * 32 + mi * 16 + q * 4 + r;
                    int t = t0 + trow;
                    float w = 0.f;
                    if (s <= t) {
                        float v = fminf(fmaxf(sacc[mi][ni][r] * 0.125f, -80.f), 80.f);
                        float x = attn_bias[((size_t)bh * TT + t) * SS + s];
                        float e = __expf(-2.f * fabsf(x));
                        float th = copysignf((1.f - e) / (1.f + e), x);
                        float scl = fmaxf(1.f + bs * th, 1e-9f);
                        w = __expf(v - rstat[trow]) * scl;
                        rs[mi][r] += w;
                    }
                    Ws[trow * 136 + sc_] = f2b(w);
                }
            }
        __syncthreads();

        // w tile -> global wbuf (vectorized)
        #pragma unroll
        for (int o = 0; o < 4; o++) {
            int idx = o * 256 + tid;
            int row_ = idx >> 4, c_ = idx & 15;
            uint4 u = *(const uint4*)&Ws[row_ * 136 + c_ * 8];
            *(uint4*)&wbuf[((size_t)bh * TT + t0 + row_) * SS + s0 + c_ * 8] = u;
        }

        // O += W . V
        #pragma unroll
        for (int ks = 0; ks < 4; ks++) {
            bf16x8 af[2], bf2[2];
            #pragma unroll
            for (int mi = 0; mi < 2; mi++) {
                int row_ = mq * 32 + mi * 16 + l15;
                af[mi] = *(const bf16x8*)&Ws[row_ * 136 + (ks * 4 + q) * 8];
            }
            #pragma unroll
            for (int ni = 0; ni < 2; ni++) {
                int vr = nq * 32 + ni * 16 + l15;
                bf2[ni] = *(const bf16x8*)&Vs[vr * 128 + ((ks * 4 + q) ^ (vr & 15)) * 8];
            }
            #pragma unroll
            for (int mi = 0; mi < 2; mi++)
                #pragma unroll
                for (int ni = 0; ni < 2; ni++)
                    oacc[mi][ni] = __builtin_amdgcn_mfma_f32_16x16x32_bf16(af[mi], bf2[ni], oacc[mi][ni], 0, 0, 0);
        }
        __syncthreads();
    }

    // ---- l2 finalize -> rstat = inv_l2 ----
    #pragma unroll
    for (int mi = 0; mi < 2; mi++)
        #pragma unroll
        for (int r = 0; r < 4; r++) {
            float v = rs[mi][r];
            v += __shfl_xor(v, 1);
            v += __shfl_xor(v, 2);
            v += __shfl_xor(v, 4);
            v += __shfl_xor(v, 8);
            rs[mi][r] = v;
        }
    if (l15 == 0) {
        #pragma unroll
        for (int mi = 0; mi < 2; mi++)
            #pragma unroll
            for (int r = 0; r < 4; r++)
                rsum_p[nq][mq * 32 + mi * 16 + q * 4 + r] = rs[mi][r];
    }
    __syncthreads();
    if (tid < 64) rstat[tid] = 1.f / (rsum_p[0][tid] + rsum_p[1][tid]);
    __syncthreads();

    // ---- P3: attn = w * inv_l2 (fp32), zero-fill s >= nst*128 ----
    const int cend = nst * 128;
    for (int idx = tid; idx < 64 * 256; idx += 256) {
        int row_ = idx >> 8;
        int c4 = (idx & 255) * 4;
        float4 o4;
        if (c4 < cend) {
            uint2 u = *(const uint2*)&wbuf[((size_t)bh * TT + t0 + row_) * SS + c4];
            float inv = rstat[row_];
            union { unsigned uu; float ff; } a0, a1, a2, a3;
            a0.uu = (u.x & 0xffffu) << 16; a1.uu = (u.x & 0xffff0000u);
            a2.uu = (u.y & 0xffffu) << 16; a3.uu = (u.y & 0xffff0000u);
            o4.x = a0.ff * inv; o4.y = a1.ff * inv; o4.z = a2.ff * inv; o4.w = a3.ff * inv;
        } else {
            o4.x = 0.f; o4.y = 0.f; o4.z = 0.f; o4.w = 0.f;
        }
        *(float4*)&attn[((size_t)bh * TT + t0 + row_) * SS + c4] = o4;
    }

    // ---- P4: ao = O * inv_l2 (bf16) ----
    #pragma unroll
    for (int mi = 0; mi < 2; mi++)
        #pragma unroll
        for (int ni = 0; ni < 2; ni++)
            #pragma unroll
            for (int r = 0; r < 4; r++) {
                int row_ = mq * 32 + mi * 16 + q * 4 + r;
                int col = nq * 32 + ni * 16 + l15;
                ao[(size_t)(b * TT + t0 + row_) * DD + h * DH + col] =
                    f2b(oacc[mi][ni][r] * rstat[row_]);
            }
}

// ---------------------------------------------------------------------------
extern "C" void kernel_launch(void* const* d_in, const int* in_sizes, int n_in,
                              void* d_out, int out_size, void* d_ws, size_t ws_size,
                              hipStream_t stream)
{
    const float* q   = (const float*)d_in[0];
    const float* k   = (const float*)d_in[1];
    const float* v   = (const float*)d_in[2];
    const float* attn_bias = (const float*)d_in[4];
    const float* Wq = (const float*)d_in[5];
    const float* bq = (const float*)d_in[6];
    const float* Wk = (const float*)d_in[7];
    const float* bk = (const float*)d_in[8];
    const float* Wv = (const float*)d_in[9];
    const float* bv = (const float*)d_in[10];
    const float* Wo = (const float*)d_in[11];
    const float* bo = (const float*)d_in[12];
    const float* bscale = (const float*)d_in[13];

    char* base = (char*)d_ws;   // d_ws is ~544 MiB (fill WRITE_SIZE evidence)
    ushort_t* qb   = (ushort_t*)(base + (0ull  << 20));  // 4 MB
    ushort_t* kb   = (ushort_t*)(base + (4ull  << 20));  // 4 MB
    ushort_t* vb   = (ushort_t*)(base + (8ull  << 20));  // 4 MB
    ushort_t* Wqb  = (ushort_t*)(base + (12ull << 20));  // 2 MB
    ushort_t* Wkb  = (ushort_t*)(base + (14ull << 20));  // 2 MB
    ushort_t* Wvb  = (ushort_t*)(base + (16ull << 20));  // 2 MB
    ushort_t* Wob  = (ushort_t*)(base + (18ull << 20));  // 2 MB
    ushort_t* qhb  = (ushort_t*)(base + (20ull << 20));  // 4 MB
    ushort_t* khb  = (ushort_t*)(base + (24ull << 20));  // 4 MB
    ushort_t* vhb  = (ushort_t*)(base + (28ull << 20));  // 4 MB
    ushort_t* vT   = (ushort_t*)(base + (32ull << 20));  // 4 MB
    ushort_t* aob  = (ushort_t*)(base + (36ull << 20));  // 4 MB
    ushort_t* wbuf = (ushort_t*)(base + (40ull << 20));  // 64 MB

    float* out  = (float*)d_out;
    float* attn = out + (size_t)BB * TT * DD;

    cvt_all<<<dim3(1024, 7), 256, 0, stream>>>(q, k, v, Wq, Wk, Wv, Wo,
                                               qb, kb, vb, Wqb, Wkb, Wvb, Wob);
    proj_gemm<<<dim3(8, 16, 3), 256, 0, stream>>>(qb, kb, vb, Wqb, Wkb, Wvb,
                                                  bq, bk, bv, qhb, khb, vhb);
    transpose_v<<<dim3(16, 32), 256, 0, stream>>>(vhb, vT);
    flash_attn<<<dim3(16, 32), 256, 0, stream>>>(qhb, khb, vT, attn_bias, bscale,
                                                 wbuf, aob, attn);
    oproj_gemm<<<dim3(8, 16), 256, 0, stream>>>(aob, Wob, bo, out);
}